// Round 1
// baseline (614.421 us; speedup 1.0000x reference)
//
#include <hip/hip_runtime.h>
#include <hip/hip_bf16.h>

// Problem constants (from reference):
// B=16, S=4096, H=512 ; G=2, V=320, D=256 (d = D/G = 128)
constexpr int BT = 16 * 4096;   // 65536 rows
constexpr int K  = 512;         // H
constexpr int V  = 320;         // codes per group
constexpr int G  = 2;           // groups
constexpr int Dg = 128;         // code dim per group
constexpr int MT = 32;          // rows per block
constexpr int KB = 16;          // K panel

// Fused GEMM(32x320x512 fp32) + argmax + gather + histogram.
// Grid: (BT/MT, G). Block: 256 threads.
// Thread map: rp = tid>>4 (rows 2rp,2rp+1), cg = tid&15 (cols cg*20..cg*20+19).
__global__ __launch_bounds__(256) void vq_main(
    const float* __restrict__ hs, const float* __restrict__ Wm,
    const float* __restrict__ bv, const float* __restrict__ cb,
    float* __restrict__ out, unsigned int* __restrict__ hist)
{
    __shared__ float hs_s[KB][MT + 2];   // stride 34: staging-write + read both conflict-free, 8B aligned
    __shared__ float W_s[KB][V];         // stride 320: writes contiguous, reads kk-uniform
    __shared__ float red_v[MT][16];
    __shared__ int   red_i[MT][16];
    __shared__ int   idx_s[MT];

    const int tid = threadIdx.x;
    const int bm  = blockIdx.x;
    const int g   = blockIdx.y;
    const int r0  = bm * MT;

    const int rp  = tid >> 4;    // 0..15
    const int cg  = tid & 15;    // 0..15
    const int cb0 = cg * 20;     // col base within group

    float acc0[20], acc1[20];
#pragma unroll
    for (int j = 0; j < 20; ++j) {
        float b0 = bv[g * V + cb0 + j];
        acc0[j] = b0; acc1[j] = b0;
    }

    // staging index precompute (invariant over kt)
    const int st_row = tid >> 4;   // 0..15 (loads rows st_row, st_row+16)
    const int st_kk  = tid & 15;

    for (int kt = 0; kt < K; kt += KB) {
        // ---- stage hs panel: 32 rows x 16 k ----
        hs_s[st_kk][st_row]      = hs[(size_t)(r0 + st_row) * K + kt + st_kk];
        hs_s[st_kk][st_row + 16] = hs[(size_t)(r0 + st_row + 16) * K + kt + st_kk];
        // ---- stage W panel: 16 k x 320 cols (1280 float4, 5 per thread) ----
#pragma unroll
        for (int rep = 0; rep < 5; ++rep) {
            int idx = rep * 256 + tid;     // 0..1279
            int kk  = idx / 80;            // 80 float4 per row
            int c4  = idx - kk * 80;
            float4 w4 = *reinterpret_cast<const float4*>(
                &Wm[(size_t)(kt + kk) * (G * V) + g * V + c4 * 4]);
            *reinterpret_cast<float4*>(&W_s[kk][c4 * 4]) = w4;
        }
        __syncthreads();
        // ---- compute ----
#pragma unroll
        for (int kk = 0; kk < KB; ++kk) {
            float2 h = *reinterpret_cast<const float2*>(&hs_s[kk][rp * 2]);
#pragma unroll
            for (int j4 = 0; j4 < 5; ++j4) {
                float4 w = *reinterpret_cast<const float4*>(&W_s[kk][cb0 + j4 * 4]);
                acc0[j4*4+0] += h.x * w.x;  acc1[j4*4+0] += h.y * w.x;
                acc0[j4*4+1] += h.x * w.y;  acc1[j4*4+1] += h.y * w.y;
                acc0[j4*4+2] += h.x * w.z;  acc1[j4*4+2] += h.y * w.z;
                acc0[j4*4+3] += h.x * w.w;  acc1[j4*4+3] += h.y * w.w;
            }
        }
        __syncthreads();
    }

    // ---- thread-local argmax (ascending cols, strict > => first occurrence) ----
    float v0 = acc0[0]; int i0 = 0;
    float v1 = acc1[0]; int i1 = 0;
#pragma unroll
    for (int j = 1; j < 20; ++j) {
        if (acc0[j] > v0) { v0 = acc0[j]; i0 = j; }
        if (acc1[j] > v1) { v1 = acc1[j]; i1 = j; }
    }
    red_v[rp * 2][cg]     = v0;  red_i[rp * 2][cg]     = cb0 + i0;
    red_v[rp * 2 + 1][cg] = v1;  red_i[rp * 2 + 1][cg] = cb0 + i1;
    __syncthreads();

    // ---- per-row reduce across 16 col-groups (ascending cg => first occurrence) ----
    if (tid < MT) {
        float bvv = red_v[tid][0]; int bi = red_i[tid][0];
#pragma unroll
        for (int c = 1; c < 16; ++c) {
            if (red_v[tid][c] > bvv) { bvv = red_v[tid][c]; bi = red_i[tid][c]; }
        }
        idx_s[tid] = bi;
        atomicAdd(&hist[g * V + bi], 1u);
    }
    __syncthreads();

    // ---- gather: 32 rows x 128 floats = 1024 float4, 4 per thread ----
#pragma unroll
    for (int rep = 0; rep < 4; ++rep) {
        int idx = rep * 256 + tid;     // 0..1023
        int row = idx >> 5;            // 32 float4 per row
        int d4  = idx & 31;
        int vi  = idx_s[row];
        float4 val = *reinterpret_cast<const float4*>(
            &cb[((size_t)(g * V + vi)) * Dg + d4 * 4]);
        *reinterpret_cast<float4*>(
            &out[((size_t)(r0 + row)) * (G * Dg) + g * Dg + d4 * 4]) = val;
    }
}

// Perplexity from histogram: one wave.
__global__ void vq_ppl(const unsigned int* __restrict__ hist, float* __restrict__ outp)
{
    int lane = threadIdx.x;  // 64
    float ppl = 0.0f;
    for (int g = 0; g < G; ++g) {
        float local = 0.0f;
        for (int v = lane; v < V; v += 64) {
            float m = (float)hist[g * V + v] * (1.0f / (float)BT);
            local += m * logf(m + 1e-7f);
        }
#pragma unroll
        for (int off = 32; off; off >>= 1) local += __shfl_down(local, off);
        if (lane == 0) ppl += expf(-local);
    }
    if (lane == 0) outp[0] = ppl;
}

extern "C" void kernel_launch(void* const* d_in, const int* in_sizes, int n_in,
                              void* d_out, int out_size, void* d_ws, size_t ws_size,
                              hipStream_t stream)
{
    const float* hs = (const float*)d_in[0];   // (B,S,H)
    const float* Wm = (const float*)d_in[1];   // (H, G*V)
    const float* bv = (const float*)d_in[2];   // (G*V,)
    const float* cb = (const float*)d_in[3];   // (1, G*V, Dg)
    float* out = (float*)d_out;                // BT*G*Dg floats, then 1 float perplexity
    unsigned int* hist = (unsigned int*)d_ws;  // G*V counters

    hipMemsetAsync(d_ws, 0, G * V * sizeof(unsigned int), stream);

    dim3 grid(BT / MT, G);
    vq_main<<<grid, 256, 0, stream>>>(hs, Wm, bv, cb, out, hist);
    vq_ppl<<<1, 64, 0, stream>>>(hist, out + (size_t)BT * G * Dg);
}